// Round 13
// baseline (415.880 us; speedup 1.0000x reference)
//
#include <hip/hip_runtime.h>
#include <hip/hip_bf16.h>

#define V 50000
#define D 128
#define EF 16
#define E_EDGES 800000
#define NIT 6250              // E/128 double-tiles (exact)
#define USTR 136              // Us/Cs LDS row stride (2B elems): 272B
#define XESTR 40              // Xe LDS row stride (ushorts): 80B, b128-aligned
#define NSCAN 196             // ceil(V/256)
#define EGRID 768             // 3 blocks/CU * 256 CU (LDS-limited to 3)
#define UGRID 782             // ceil(V/64)

typedef __attribute__((ext_vector_type(8))) __bf16 bf16x8;
typedef __attribute__((ext_vector_type(4))) float f32x4;
typedef __attribute__((ext_vector_type(2))) __fp16 fp16x2;

__device__ inline unsigned short f2bf(float f) {
    unsigned u = __float_as_uint(f);
    u += 0x7FFF + ((u >> 16) & 1);   // RNE
    return (unsigned short)(u >> 16);
}
__device__ inline unsigned pack2(float a, float b) {
    return (unsigned)f2bf(a) | ((unsigned)f2bf(b) << 16);
}
__device__ inline float bf2f(unsigned short u) {
    return __uint_as_float((unsigned)u << 16);
}
__device__ inline unsigned pkbf(float a, float b) {   // packed RNE bf16 pair
    union { __hip_bfloat162 h; unsigned u; } v;
    v.h = __float22bfloat162_rn(make_float2(a, b));
    return v.u;
}
__device__ inline unsigned pkf16(float a, float b) {  // packed RTZ f16 pair
    union { fp16x2 h; unsigned u; } v;
    v.h = __builtin_amdgcn_cvt_pkrtz(a, b);
    return v.u;
}

// ---- merged setup: zero agg + dst histogram + pack weights + U-GEMM ----
__global__ __launch_bounds__(256)
void setup_kernel(const float* __restrict__ h, const int* __restrict__ ei,
                  int* __restrict__ cnt, float* __restrict__ agg,
                  const float* __restrict__ W1, const float* __restrict__ W2,
                  unsigned short* __restrict__ W1p, unsigned short* __restrict__ W2p,
                  unsigned short* __restrict__ U) {
    __shared__ __align__(16) unsigned short Hs[64 * USTR];
    const int tid = threadIdx.x;
    int idx = blockIdx.x * 256 + tid;                  // 1,600,000 exact
    *(float4*)(agg + ((size_t)idx << 2)) = (float4){0.f, 0.f, 0.f, 0.f};
    if (idx < E_EDGES) atomicAdd(&cnt[ei[E_EDGES + idx]], 1);
    if (idx < 5 * 128 * 32) {
        int kb = idx >> 12, rem = idx & 4095;
        int n = rem >> 5, kk = rem & 31;
        int k = kb * 32 + kk;
        W1p[idx] = f2bf((k < D + EF) ? W1[k * D + n] : 0.0f);
    }
    if (idx < 4 * 128 * 32) {
        int kb = idx >> 12, rem = idx & 4095;
        int n = rem >> 5, kk = rem & 31;
        W2p[idx] = f2bf(W2[(kb * 32 + kk) * D + n]);
    }
    if (blockIdx.x >= UGRID) return;

    // ---- U-GEMM role ----
    const int lane = tid & 63;
    const int wave = tid >> 6;
    const int nlo  = lane & 15;
    const int kq   = lane >> 4;
    const int er   = tid >> 4;
    const int ec   = tid & 15;
    const int gbase = blockIdx.x << 6;

    bf16x8 B1[4][2];
    #pragma unroll
    for (int t = 0; t < 2; ++t) {
        int n = wave * 32 + t * 16 + nlo;
        #pragma unroll
        for (int kb = 0; kb < 4; ++kb) {
            union { bf16x8 v; unsigned short s[8]; } f;
            #pragma unroll
            for (int j = 0; j < 8; ++j)
                f.s[j] = f2bf(W1[(kb * 32 + (kq << 3) + j) * D + n]);
            B1[kb][t] = f.v;
        }
    }

    #pragma unroll
    for (int m = 0; m < 4; ++m) {
        int row = er + m * 16;
        int grow = gbase + row;
        unsigned* o = (unsigned*)(Hs + row * USTR + (ec << 3));
        if (grow < V) {
            const float4* p = (const float4*)(h + (size_t)grow * D + (ec << 3));
            float4 v0 = p[0], v1 = p[1];
            o[0] = pack2(v0.x, v0.y); o[1] = pack2(v0.z, v0.w);
            o[2] = pack2(v1.x, v1.y); o[3] = pack2(v1.z, v1.w);
        } else {
            o[0] = 0u; o[1] = 0u; o[2] = 0u; o[3] = 0u;
        }
    }
    __syncthreads();

    f32x4 acc[4][2];
    #pragma unroll
    for (int mt = 0; mt < 4; ++mt)
        #pragma unroll
        for (int t = 0; t < 2; ++t)
            acc[mt][t] = (f32x4){0.f, 0.f, 0.f, 0.f};

    #pragma unroll
    for (int kb = 0; kb < 4; ++kb) {
        bf16x8 A[4];
        int ko = kb * 32 + (kq << 3);
        #pragma unroll
        for (int mt = 0; mt < 4; ++mt)
            A[mt] = *(const bf16x8*)(Hs + (mt * 16 + nlo) * USTR + ko);
        #pragma unroll
        for (int mt = 0; mt < 4; ++mt)
            #pragma unroll
            for (int t = 0; t < 2; ++t)
                acc[mt][t] = __builtin_amdgcn_mfma_f32_16x16x32_bf16(A[mt], B1[kb][t], acc[mt][t], 0, 0, 0);
    }

    #pragma unroll
    for (int mt = 0; mt < 4; ++mt)
        #pragma unroll
        for (int t = 0; t < 2; ++t)
            #pragma unroll
            for (int r = 0; r < 4; ++r) {
                int row = mt * 16 + (kq << 2) + r;
                int grow = gbase + row;
                int col = wave * 32 + t * 16 + nlo;
                if (grow < V)
                    U[(size_t)grow * D + col] = f2bf(acc[mt][t][r]);
            }
}

// ---- counting sort ----------------------------------------------------
__device__ inline int block_excl_scan(int x, int t, int* ws) {
    int lane = t & 63, w = t >> 6;
    int inc = x;
    #pragma unroll
    for (int off = 1; off < 64; off <<= 1) {
        int y = __shfl_up(inc, off);
        if (lane >= off) inc += y;
    }
    if (lane == 63) ws[w] = inc;
    __syncthreads();
    if (t == 0) {
        int r = 0;
        #pragma unroll
        for (int i = 0; i < 4; ++i) { int c = ws[i]; ws[i] = r; r += c; }
    }
    __syncthreads();
    return inc - x + ws[w];
}

__global__ __launch_bounds__(256)
void scan1_kernel(const int* __restrict__ cnt, int* __restrict__ cursor,
                  int* __restrict__ bsum) {
    __shared__ int ws[4];
    __shared__ int tot;
    int t = threadIdx.x;
    int i = blockIdx.x * 256 + t;
    int x = (i < V) ? cnt[i] : 0;
    int ex = block_excl_scan(x, t, ws);
    if (i < V) cursor[i] = ex;
    if (t == 255) tot = ex + x;
    __syncthreads();
    if (t == 0) bsum[blockIdx.x] = tot;
}

// scatter + fused block-offset scan: writes sorted srcs/dsts/eidx
__global__ __launch_bounds__(256)
void scatter_kernel(const int* __restrict__ ei, int* __restrict__ cursor,
                    const int* __restrict__ bsum,
                    int* __restrict__ srcs, int* __restrict__ dsts,
                    int* __restrict__ eidx) {
    __shared__ int ws[4];
    __shared__ int sboff[NSCAN];
    int t = threadIdx.x;
    int x = (t < NSCAN) ? bsum[t] : 0;
    int ex = block_excl_scan(x, t, ws);
    if (t < NSCAN) sboff[t] = ex;
    __syncthreads();
    int e = blockIdx.x * 256 + t;                      // 3125*256 = E exact
    int d = ei[E_EDGES + e];
    int pos = atomicAdd(&cursor[d], 1) + sboff[d >> 8];
    srcs[pos] = ei[e];
    dsts[pos] = d;
    eidx[pos] = e;
}

// ---- edge MLP + segmented scatter (128-edge double tile) --------------
// 128 edges per iteration: 5 barriers / 128 edges (2.5 per 64, vs R9's 3)
// and every phase is 2x longer -> fixed per-barrier drain cost amortized.
// Us/Cs re-union (45.6KB LDS -> 3 blocks/CU); the scan->staging hazard is
// handled by the post-scan barrier. Stage1 in two mt-halves (accE[4][2])
// to cap VGPR; stage2 needs acc2[8][2] (Cs write must follow ALL waves'
// Y reads -> single bar3). R9's proven pieces kept verbatim: swapped
// MFMA, b64 epilogues, R5 col-owner scan, 1-tile-ahead gathers after the
// last pre-scan barrier. launch_bounds(256,3): VGPR cap ~170 (est ~155).
__global__ __launch_bounds__(256, 3)
void edge_kernel(const unsigned short* __restrict__ U,
                 const float* __restrict__ ea,
                 const int* __restrict__ srcs, const int* __restrict__ dsts,
                 const int* __restrict__ eidx,
                 const unsigned short* __restrict__ W1p, const unsigned short* __restrict__ W2p,
                 const float* __restrict__ b1, const float* __restrict__ b2,
                 float* __restrict__ agg) {
    union SU {
        unsigned short Us[128 * USTR];   // 34,816 B (U rows -> in-place Y)
        _Float16 Cs[128 * USTR];         // 34,816 B
    };
    __shared__ __align__(16) SU u;
    __shared__ __align__(16) unsigned short Xe[128 * XESTR];  // 10,240 B
    __shared__ int sDst[128];                                 //    512 B

    const int tid  = threadIdx.x;
    const int lane = tid & 63;
    const int wave = tid >> 6;      // owns N cols [wave*32, wave*32+32)
    const int nlo  = lane & 15;
    const int kq   = lane >> 4;
    const int er   = tid >> 4;      // gather row base 0..15 (+16*k, k=0..7)
    const int ec   = tid & 15;      // gather 16B chunk 0..15
    const int ee2  = tid >> 1;      // ea row 0..127
    const int eq2  = tid & 1;       // ea half-row (8 floats)

    // Persistent W fragments (swapped-MFMA A-operands)
    bf16x8 B1e[2], B2[4][2];
    float4 b1n[2], b2n[2];          // bias along n = wave*32 + t*16 + kq*4 + r
    #pragma unroll
    for (int t = 0; t < 2; ++t) {
        int n = wave * 32 + t * 16 + nlo;
        b1n[t] = *(const float4*)(b1 + wave * 32 + t * 16 + (kq << 2));
        b2n[t] = *(const float4*)(b2 + wave * 32 + t * 16 + (kq << 2));
        B1e[t] = *(const bf16x8*)(W1p + ((4 << 7) + n) * 32 + (kq << 3));
        #pragma unroll
        for (int kb = 0; kb < 4; ++kb)
            B2[kb][t] = *(const bf16x8*)(W2p + ((kb << 7) + n) * 32 + (kq << 3));
    }

    // zero Xe K-pad (ushort cols 16..31) once; never overwritten afterwards
    #pragma unroll
    for (int j = 0; j < 4; ++j) {
        int idx = (tid << 2) + j;               // 0..1023
        ((unsigned*)Xe)[(idx >> 3) * (XESTR / 2) + 8 + (idx & 7)] = 0u;
    }

    // ---- pipeline prologue ----
    const int base0 = blockIdx.x << 7;
    int dd = (tid < 128) ? dsts[base0 + tid] : 0;
    bf16x8 pf[8];
    {
        int s[8];
        #pragma unroll
        for (int k = 0; k < 8; ++k) s[k] = srcs[base0 + er + (k << 4)];
        #pragma unroll
        for (int k = 0; k < 8; ++k)
            pf[k] = *(const bf16x8*)(U + (size_t)s[k] * D + (ec << 3));
    }
    int ae0 = eidx[base0 + ee2];
    float4 pe0 = *(const float4*)(ea + (size_t)ae0 * EF + (eq2 << 3));
    float4 pe1 = *(const float4*)(ea + (size_t)ae0 * EF + (eq2 << 3) + 4);

    // iter+G indexes
    int n1 = blockIdx.x + EGRID;
    int nb1 = (n1 < NIT ? n1 : blockIdx.x) << 7;
    int j1s[8];
    #pragma unroll
    for (int k = 0; k < 8; ++k) j1s[k] = srcs[nb1 + er + (k << 4)];
    int j1e = eidx[nb1 + ee2];
    int j1d = (tid < 128) ? dsts[nb1 + tid] : 0;

    for (int it = blockIdx.x; it < NIT; it += EGRID) {
        // staging: 128 U rows + 128 ea rows; vmcnt wait on pf/pe lands here
        if (tid < 128) sDst[tid] = dd;
        #pragma unroll
        for (int k = 0; k < 8; ++k)
            *(bf16x8*)(u.Us + (er + (k << 4)) * USTR + (ec << 3)) = pf[k];
        {
            unsigned* xp = (unsigned*)Xe + ee2 * (XESTR / 2) + (eq2 << 2);
            xp[0] = pkbf(pe0.x, pe0.y);
            xp[1] = pkbf(pe0.z, pe0.w);
            xp[2] = pkbf(pe1.x, pe1.y);
            xp[3] = pkbf(pe1.z, pe1.w);
        }
        __syncthreads();                                    // bar1: staging done

        // ---- Stage 1 (swapped, two mt-halves): Y = relu(U + Xe@W1e + b1)
        #pragma unroll
        for (int mtb = 0; mtb < 8; mtb += 4) {
            f32x4 accE[4][2];
            #pragma unroll
            for (int i = 0; i < 4; ++i)
                #pragma unroll
                for (int t = 0; t < 2; ++t) {
                    uint2 uu = *(const uint2*)(u.Us + ((mtb + i) * 16 + nlo) * USTR + wave * 32 + t * 16 + (kq << 2));
                    accE[i][t][0] = bf2f((unsigned short)uu.x);
                    accE[i][t][1] = bf2f((unsigned short)(uu.x >> 16));
                    accE[i][t][2] = bf2f((unsigned short)uu.y);
                    accE[i][t][3] = bf2f((unsigned short)(uu.y >> 16));
                }
            bf16x8 Xf[4];
            #pragma unroll
            for (int i = 0; i < 4; ++i)
                Xf[i] = *(const bf16x8*)(Xe + ((mtb + i) * 16 + nlo) * XESTR + (kq << 3));
            #pragma unroll
            for (int i = 0; i < 4; ++i)
                #pragma unroll
                for (int t = 0; t < 2; ++t)
                    accE[i][t] = __builtin_amdgcn_mfma_f32_16x16x32_bf16(B1e[t], Xf[i], accE[i][t], 0, 0, 0);
            #pragma unroll
            for (int i = 0; i < 4; ++i)
                #pragma unroll
                for (int t = 0; t < 2; ++t) {
                    uint2 yw;
                    yw.x = pkbf(fmaxf(accE[i][t][0] + b1n[t].x, 0.0f),
                                fmaxf(accE[i][t][1] + b1n[t].y, 0.0f));
                    yw.y = pkbf(fmaxf(accE[i][t][2] + b1n[t].z, 0.0f),
                                fmaxf(accE[i][t][3] + b1n[t].w, 0.0f));
                    *(uint2*)(u.Us + ((mtb + i) * 16 + nlo) * USTR + wave * 32 + t * 16 + (kq << 2)) = yw;
                }
        }
        __syncthreads();                                    // bar2: Y ready

        // A: issue index loads for it+2G (in flight across stage2 + scan)
        int n2 = it + 2 * EGRID;
        int nb2 = (n2 < NIT ? n2 : it) << 7;
        int j2s[8];
        #pragma unroll
        for (int k = 0; k < 8; ++k) j2s[k] = srcs[nb2 + er + (k << 4)];
        int j2e = eidx[nb2 + ee2];
        int j2d = (tid < 128) ? dsts[nb2 + tid] : 0;

        // ---- Stage 2 (swapped): C[128,128] = Y @ W2 ----
        f32x4 acc2[8][2];
        #pragma unroll
        for (int mt = 0; mt < 8; ++mt)
            #pragma unroll
            for (int t = 0; t < 2; ++t)
                acc2[mt][t] = (f32x4){0.f, 0.f, 0.f, 0.f};

        #pragma unroll
        for (int kb = 0; kb < 4; ++kb) {
            bf16x8 Yf[8];
            int ko = kb * 32 + (kq << 3);
            #pragma unroll
            for (int mt = 0; mt < 8; ++mt)
                Yf[mt] = *(const bf16x8*)(u.Us + (mt * 16 + nlo) * USTR + ko);
            #pragma unroll
            for (int mt = 0; mt < 8; ++mt)
                #pragma unroll
                for (int t = 0; t < 2; ++t)
                    acc2[mt][t] = __builtin_amdgcn_mfma_f32_16x16x32_bf16(B2[kb][t], Yf[mt], acc2[mt][t], 0, 0, 0);
        }
        __syncthreads();                                    // bar3: all Y reads done

        // C = f16(acc2 + b2) -> Cs[m][n] (union; safe after bar3)
        #pragma unroll
        for (int mt = 0; mt < 8; ++mt)
            #pragma unroll
            for (int t = 0; t < 2; ++t) {
                uint2 cw;
                cw.x = pkf16(acc2[mt][t][0] + b2n[t].x, acc2[mt][t][1] + b2n[t].y);
                cw.y = pkf16(acc2[mt][t][2] + b2n[t].z, acc2[mt][t][3] + b2n[t].w);
                *(uint2*)((unsigned short*)u.Cs + (size_t)(mt * 16 + nlo) * USTR + wave * 32 + t * 16 + (kq << 2)) = cw;
            }
        __syncthreads();                                    // bar4: Cs ready

        // C: issue data gathers for it+G; no barrier before their vmcnt
        // wait at next staging -> latency hides under the 64-row scan.
        bf16x8 qf[8];
        #pragma unroll
        for (int k = 0; k < 8; ++k)
            qf[k] = *(const bf16x8*)(U + (size_t)j1s[k] * D + (ec << 3));
        float4 qe0 = *(const float4*)(ea + (size_t)j1e * EF + (eq2 << 3));
        float4 qe1 = *(const float4*)(ea + (size_t)j1e * EF + (eq2 << 3) + 4);
        int nd = j1d;

        // segmented run-reduction over sorted dst (R5 pattern): thread owns
        // one column; 2 groups x 64 rows; one coalesced atomicAdd per flush.
        {
            int col = tid & 127;
            int rbase = (tid >> 7) << 6;            // rows [rbase, rbase+64)
            float sum = 0.f;
            int cur = sDst[rbase];
            for (int i = 0; i < 64; ++i) {
                int d = sDst[rbase + i];            // wave-uniform broadcast
                if (d != cur) {
                    atomicAdd(&agg[(size_t)cur * D + col], sum);
                    sum = 0.f;
                    cur = d;
                }
                sum += (float)u.Cs[(rbase + i) * USTR + col];
            }
            atomicAdd(&agg[(size_t)cur * D + col], sum);
        }
        __syncthreads();                                    // bar5: scan done before union restaged

        // rotate pipeline registers
        #pragma unroll
        for (int k = 0; k < 8; ++k) { pf[k] = qf[k]; j1s[k] = j2s[k]; }
        pe0 = qe0; pe1 = qe1; dd = nd;
        j1e = j2e; j1d = j2d;
    }
}

// out = LayerNorm(h + agg/(1+deg)) * gamma + beta ; one wave per node
__global__ __launch_bounds__(256)
void finalize_kernel(const float* __restrict__ h, const float* __restrict__ agg,
                     const int* __restrict__ cnt,
                     const float* __restrict__ gamma, const float* __restrict__ beta,
                     float* __restrict__ out) {
    int wave = threadIdx.x >> 6, lane = threadIdx.x & 63;
    int v = blockIdx.x * 4 + wave;
    if (v >= V) return;
    float inv = 1.0f / (1.0f + (float)cnt[v]);
    const float* hr = h + (size_t)v * D;
    const float* ar = agg + (size_t)v * D;
    float x0 = hr[lane]      + ar[lane]      * inv;
    float x1 = hr[lane + 64] + ar[lane + 64] * inv;
    float s = x0 + x1;
    #pragma unroll
    for (int m = 32; m; m >>= 1) s += __shfl_xor(s, m);
    float mu = s * (1.0f / 128.0f);
    float d0 = x0 - mu, d1 = x1 - mu;
    float vs = d0 * d0 + d1 * d1;
    #pragma unroll
    for (int m = 32; m; m >>= 1) vs += __shfl_xor(vs, m);
    float rs = rsqrtf(vs * (1.0f / 128.0f) + 1e-5f);
    out[(size_t)v * D + lane]      = d0 * rs * gamma[lane]      + beta[lane];
    out[(size_t)v * D + 64 + lane] = d1 * rs * gamma[lane + 64] + beta[lane + 64];
}

extern "C" void kernel_launch(void* const* d_in, const int* in_sizes, int n_in,
                              void* d_out, int out_size, void* d_ws, size_t ws_size,
                              hipStream_t stream) {
    const float* h     = (const float*)d_in[0];
    const int*   ei    = (const int*)d_in[1];     // [2,E]: row0=src, row1=dst
    const float* ea    = (const float*)d_in[2];
    const float* W1    = (const float*)d_in[3];
    const float* b1    = (const float*)d_in[4];
    const float* W2    = (const float*)d_in[5];
    const float* b2    = (const float*)d_in[6];
    const float* gamma = (const float*)d_in[7];
    const float* beta  = (const float*)d_in[8];
    float* out = (float*)d_out;

    char* ws = (char*)d_ws;
    float*          agg    = (float*)ws;                          // 25,600,000
    int*            cnt    = (int*)(ws + 25600000);               //    200,000 (deg)
    int*            cursor = (int*)(ws + 25800000);               //    200,000
    int*            bsum   = (int*)(ws + 26000000);               //        800
    int*            srcs   = (int*)(ws + 26000800);               //  3,200,000
    int*            dsts   = (int*)(ws + 29200800);               //  3,200,000
    int*            eidx   = (int*)(ws + 32400800);               //  3,200,000
    unsigned short* W1p    = (unsigned short*)(ws + 35600800);    //     40,960
    unsigned short* W2p    = (unsigned short*)(ws + 35641760);    //     32,768
    unsigned short* U      = (unsigned short*)(ws + 35674528);    // 12,800,000

    (void)hipMemsetAsync(cnt, 0, 200000, stream);
    setup_kernel<<<6250, 256, 0, stream>>>(h, ei, cnt, agg, W1, W2, W1p, W2p, U);
    scan1_kernel<<<NSCAN, 256, 0, stream>>>(cnt, cursor, bsum);
    scatter_kernel<<<3125, 256, 0, stream>>>(ei, cursor, bsum, srcs, dsts, eidx);
    edge_kernel<<<EGRID, 256, 0, stream>>>(U, ea, srcs, dsts, eidx, W1p, W2p, b1, b2, agg);
    finalize_kernel<<<12500, 256, 0, stream>>>(h, agg, cnt, gamma, beta, out);
}

// Round 14
// 302.360 us; speedup vs baseline: 1.3754x; 1.3754x over previous
//
#include <hip/hip_runtime.h>
#include <hip/hip_bf16.h>

#define V 50000
#define D 128
#define EF 16
#define E_EDGES 800000
#define NT 12500              // E/64 edge tiles (exact)
#define USTR 136              // Us LDS row stride (ushorts): 272B, b128-aligned
#define XESTR 40              // Xe LDS row stride (ushorts): 80B, b128-aligned
#define CSTR 136              // Cs LDS row stride (f16 elems): 272B
#define NSCAN 196             // ceil(V/256)
#define EGRID 1024            // 4 blocks/CU * 256 CU
#define UGRID 782             // ceil(V/64)

typedef __attribute__((ext_vector_type(8))) __bf16 bf16x8;
typedef __attribute__((ext_vector_type(4))) float f32x4;
typedef __attribute__((ext_vector_type(2))) __fp16 fp16x2;

__device__ inline unsigned short f2bf(float f) {
    unsigned u = __float_as_uint(f);
    u += 0x7FFF + ((u >> 16) & 1);   // RNE
    return (unsigned short)(u >> 16);
}
__device__ inline unsigned pack2(float a, float b) {
    return (unsigned)f2bf(a) | ((unsigned)f2bf(b) << 16);
}
__device__ inline float bf2f(unsigned short u) {
    return __uint_as_float((unsigned)u << 16);
}
__device__ inline unsigned pkbf(float a, float b) {   // packed RNE bf16 pair
    union { __hip_bfloat162 h; unsigned u; } v;
    v.h = __float22bfloat162_rn(make_float2(a, b));
    return v.u;
}
__device__ inline unsigned pkf16(float a, float b) {  // packed RTZ f16 pair
    union { fp16x2 h; unsigned u; } v;
    v.h = __builtin_amdgcn_cvt_pkrtz(a, b);
    return v.u;
}

// ---- merged setup: zero agg + dst histogram + pack weights + U-GEMM ----
// Blocks < UGRID additionally compute U = bf16(h @ W1[:128]) for their
// 64-node tile, self-packing B1 fragments from f32 W1 (no W1p dependency,
// so the GEMM overlaps the agg-zero instead of needing a second launch).
__global__ __launch_bounds__(256)
void setup_kernel(const float* __restrict__ h, const int* __restrict__ ei,
                  int* __restrict__ cnt, float* __restrict__ agg,
                  const float* __restrict__ W1, const float* __restrict__ W2,
                  unsigned short* __restrict__ W1p, unsigned short* __restrict__ W2p,
                  unsigned short* __restrict__ U) {
    __shared__ __align__(16) unsigned short Hs[64 * USTR];
    const int tid = threadIdx.x;
    int idx = blockIdx.x * 256 + tid;                  // 1,600,000 exact
    *(float4*)(agg + ((size_t)idx << 2)) = (float4){0.f, 0.f, 0.f, 0.f};
    if (idx < E_EDGES) atomicAdd(&cnt[ei[E_EDGES + idx]], 1);
    if (idx < 5 * 128 * 32) {
        int kb = idx >> 12, rem = idx & 4095;
        int n = rem >> 5, kk = rem & 31;
        int k = kb * 32 + kk;
        W1p[idx] = f2bf((k < D + EF) ? W1[k * D + n] : 0.0f);
    }
    if (idx < 4 * 128 * 32) {
        int kb = idx >> 12, rem = idx & 4095;
        int n = rem >> 5, kk = rem & 31;
        W2p[idx] = f2bf(W2[(kb * 32 + kk) * D + n]);
    }
    if (blockIdx.x >= UGRID) return;

    // ---- U-GEMM role ----
    const int lane = tid & 63;
    const int wave = tid >> 6;
    const int nlo  = lane & 15;
    const int kq   = lane >> 4;
    const int er   = tid >> 4;
    const int ec   = tid & 15;
    const int gbase = blockIdx.x << 6;

    bf16x8 B1[4][2];
    #pragma unroll
    for (int t = 0; t < 2; ++t) {
        int n = wave * 32 + t * 16 + nlo;
        #pragma unroll
        for (int kb = 0; kb < 4; ++kb) {
            union { bf16x8 v; unsigned short s[8]; } f;
            #pragma unroll
            for (int j = 0; j < 8; ++j)
                f.s[j] = f2bf(W1[(kb * 32 + (kq << 3) + j) * D + n]);
            B1[kb][t] = f.v;
        }
    }

    #pragma unroll
    for (int m = 0; m < 4; ++m) {
        int row = er + m * 16;
        int grow = gbase + row;
        unsigned* o = (unsigned*)(Hs + row * USTR + (ec << 3));
        if (grow < V) {
            const float4* p = (const float4*)(h + (size_t)grow * D + (ec << 3));
            float4 v0 = p[0], v1 = p[1];
            o[0] = pack2(v0.x, v0.y); o[1] = pack2(v0.z, v0.w);
            o[2] = pack2(v1.x, v1.y); o[3] = pack2(v1.z, v1.w);
        } else {
            o[0] = 0u; o[1] = 0u; o[2] = 0u; o[3] = 0u;
        }
    }
    __syncthreads();

    f32x4 acc[4][2];
    #pragma unroll
    for (int mt = 0; mt < 4; ++mt)
        #pragma unroll
        for (int t = 0; t < 2; ++t)
            acc[mt][t] = (f32x4){0.f, 0.f, 0.f, 0.f};

    #pragma unroll
    for (int kb = 0; kb < 4; ++kb) {
        bf16x8 A[4];
        int ko = kb * 32 + (kq << 3);
        #pragma unroll
        for (int mt = 0; mt < 4; ++mt)
            A[mt] = *(const bf16x8*)(Hs + (mt * 16 + nlo) * USTR + ko);
        #pragma unroll
        for (int mt = 0; mt < 4; ++mt)
            #pragma unroll
            for (int t = 0; t < 2; ++t)
                acc[mt][t] = __builtin_amdgcn_mfma_f32_16x16x32_bf16(A[mt], B1[kb][t], acc[mt][t], 0, 0, 0);
    }

    #pragma unroll
    for (int mt = 0; mt < 4; ++mt)
        #pragma unroll
        for (int t = 0; t < 2; ++t)
            #pragma unroll
            for (int r = 0; r < 4; ++r) {
                int row = mt * 16 + (kq << 2) + r;
                int grow = gbase + row;
                int col = wave * 32 + t * 16 + nlo;
                if (grow < V)
                    U[(size_t)grow * D + col] = f2bf(acc[mt][t][r]);
            }
}

// ---- counting sort ----------------------------------------------------
__device__ inline int block_excl_scan(int x, int t, int* ws) {
    int lane = t & 63, w = t >> 6;
    int inc = x;
    #pragma unroll
    for (int off = 1; off < 64; off <<= 1) {
        int y = __shfl_up(inc, off);
        if (lane >= off) inc += y;
    }
    if (lane == 63) ws[w] = inc;
    __syncthreads();
    if (t == 0) {
        int r = 0;
        #pragma unroll
        for (int i = 0; i < 4; ++i) { int c = ws[i]; ws[i] = r; r += c; }
    }
    __syncthreads();
    return inc - x + ws[w];
}

__global__ __launch_bounds__(256)
void scan1_kernel(const int* __restrict__ cnt, int* __restrict__ cursor,
                  int* __restrict__ bsum) {
    __shared__ int ws[4];
    __shared__ int tot;
    int t = threadIdx.x;
    int i = blockIdx.x * 256 + t;
    int x = (i < V) ? cnt[i] : 0;
    int ex = block_excl_scan(x, t, ws);
    if (i < V) cursor[i] = ex;
    if (t == 255) tot = ex + x;
    __syncthreads();
    if (t == 0) bsum[blockIdx.x] = tot;
}

// scatter + fused block-offset scan: writes sorted srcs/dsts/eidx
__global__ __launch_bounds__(256)
void scatter_kernel(const int* __restrict__ ei, int* __restrict__ cursor,
                    const int* __restrict__ bsum,
                    int* __restrict__ srcs, int* __restrict__ dsts,
                    int* __restrict__ eidx) {
    __shared__ int ws[4];
    __shared__ int sboff[NSCAN];
    int t = threadIdx.x;
    int x = (t < NSCAN) ? bsum[t] : 0;
    int ex = block_excl_scan(x, t, ws);
    if (t < NSCAN) sboff[t] = ex;
    __syncthreads();
    int e = blockIdx.x * 256 + t;                      // 3125*256 = E exact
    int d = ei[E_EDGES + e];
    int pos = atomicAdd(&cursor[d], 1) + sboff[d >> 8];
    srcs[pos] = ei[e];
    dsts[pos] = d;
    eidx[pos] = e;
}

// ---- edge MLP + segmented scatter (software-pipelined) ----------------
// R9 VERBATIM -- the measured local optimum (84.7us). Per tile:
// Y = relu(U[src] + ea@W1e + b1); C = Y@W2 + b2; segmented scatter.
// SWAPPED-OPERAND MFMA (W as A-operand): transposed C-fragment is
// contiguous-in-n, so acc-init / Y-write / Cs-write are b64 ops.
// 3 barriers/tile; gathers for tile+1 issued after the LAST barrier so
// they fly across the scan (1-tile-ahead is the sweet spot: R11's 2-deep
// pipeline and R13's 128-edge tile both broke regalloc and exploded HBM
// traffic). SCAN IS THE R5 ORIGINAL (R8: restructuring it amplified HBM
// writes 7x). srcs/dsts/eidx precomputed (R10: ei-resolve indirection
// costs +93MB FETCH).
__global__ __launch_bounds__(256, 4)
void edge_kernel(const unsigned short* __restrict__ U,
                 const float* __restrict__ ea,
                 const int* __restrict__ srcs, const int* __restrict__ dsts,
                 const int* __restrict__ eidx,
                 const unsigned short* __restrict__ W1p, const unsigned short* __restrict__ W2p,
                 const float* __restrict__ b1, const float* __restrict__ b2,
                 float* __restrict__ agg) {
    __shared__ __align__(16) unsigned short Us[64 * USTR];   // 17,408 B
    __shared__ __align__(16) _Float16 Cs[64 * CSTR];         // 17,408 B
    __shared__ __align__(16) unsigned short Xe[64 * XESTR];  //  5,120 B
    __shared__ int sDst[2][64];                              //    512 B

    const int tid  = threadIdx.x;
    const int lane = tid & 63;
    const int wave = tid >> 6;      // owns N cols [wave*32, wave*32+32)
    const int nlo  = lane & 15;
    const int kq   = lane >> 4;
    const int er   = tid >> 4;      // gather row base 0..15 (+16*it)
    const int ec   = tid & 15;      // gather 16B chunk 0..15
    const int ee   = tid >> 2;      // ea row 0..63
    const int eq   = tid & 3;       // ea quad

    // Persistent W fragments (same layout serves as A in swapped MFMA)
    bf16x8 B1e[2], B2[4][2];
    float4 b1n[2], b2n[2];          // bias along n = wave*32 + t*16 + kq*4 + r
    #pragma unroll
    for (int t = 0; t < 2; ++t) {
        int n = wave * 32 + t * 16 + nlo;
        b1n[t] = *(const float4*)(b1 + wave * 32 + t * 16 + (kq << 2));
        b2n[t] = *(const float4*)(b2 + wave * 32 + t * 16 + (kq << 2));
        B1e[t] = *(const bf16x8*)(W1p + ((4 << 7) + n) * 32 + (kq << 3));
        #pragma unroll
        for (int kb = 0; kb < 4; ++kb)
            B2[kb][t] = *(const bf16x8*)(W2p + ((kb << 7) + n) * 32 + (kq << 3));
    }

    // zero Xe K-pad (cols 16..31) once; never overwritten afterwards
    {
        unsigned* xz = (unsigned*)Xe;
        int i0 = tid, i1 = tid + 256;
        xz[(i0 >> 3) * (XESTR / 2) + 8 + (i0 & 7)] = 0u;
        xz[(i1 >> 3) * (XESTR / 2) + 8 + (i1 & 7)] = 0u;
    }

    // ---- pipeline prologue: data for tile0 in pf regs, indices for tile0+G
    const int base0 = blockIdx.x << 6;
    int a0 = srcs[base0 + er];
    int a1 = srcs[base0 + er + 16];
    int a2 = srcs[base0 + er + 32];
    int a3 = srcs[base0 + er + 48];
    int aev = eidx[base0 + ee];
    int ddcur = dsts[base0 + lane];
    bf16x8 pf0 = *(const bf16x8*)(U + (size_t)a0 * D + (ec << 3));
    bf16x8 pf1 = *(const bf16x8*)(U + (size_t)a1 * D + (ec << 3));
    bf16x8 pf2 = *(const bf16x8*)(U + (size_t)a2 * D + (ec << 3));
    bf16x8 pf3 = *(const bf16x8*)(U + (size_t)a3 * D + (ec << 3));
    float4 pfe = *(const float4*)(ea + (size_t)aev * EF + (eq << 2));

    int n1 = blockIdx.x + EGRID;
    int nb1 = (n1 < NT ? n1 : blockIdx.x) << 6;
    int i1s0 = srcs[nb1 + er];
    int i1s1 = srcs[nb1 + er + 16];
    int i1s2 = srcs[nb1 + er + 32];
    int i1s3 = srcs[nb1 + er + 48];
    int i1e  = eidx[nb1 + ee];
    int i1d  = dsts[nb1 + lane];

    int buf = 0;
    for (int tile = blockIdx.x; tile < NT; tile += EGRID) {
        // B: publish current tile (regs -> LDS); vmcnt wait on pf* lands here
        if (tid < 64) sDst[buf][tid] = ddcur;
        *(bf16x8*)(Us + er * USTR + (ec << 3))        = pf0;
        *(bf16x8*)(Us + (er + 16) * USTR + (ec << 3)) = pf1;
        *(bf16x8*)(Us + (er + 32) * USTR + (ec << 3)) = pf2;
        *(bf16x8*)(Us + (er + 48) * USTR + (ec << 3)) = pf3;
        {
            unsigned* xp = (unsigned*)Xe + ee * (XESTR / 2) + (eq << 1);
            xp[0] = pkbf(pfe.x, pfe.y);
            xp[1] = pkbf(pfe.z, pfe.w);
        }
        __syncthreads();                                    // bar1: staging done (drains prev scan atomics)

        // ---- Stage 1 (swapped): accE[n][m] := U^T frag, += W1e^T x Xe^T ----
        f32x4 accE[4][2];
        #pragma unroll
        for (int mt = 0; mt < 4; ++mt)
            #pragma unroll
            for (int t = 0; t < 2; ++t) {
                uint2 uu = *(const uint2*)(Us + (mt * 16 + nlo) * USTR + wave * 32 + t * 16 + (kq << 2));
                accE[mt][t][0] = bf2f((unsigned short)uu.x);
                accE[mt][t][1] = bf2f((unsigned short)(uu.x >> 16));
                accE[mt][t][2] = bf2f((unsigned short)uu.y);
                accE[mt][t][3] = bf2f((unsigned short)(uu.y >> 16));
            }
        {
            bf16x8 Xf[4];
            #pragma unroll
            for (int mt = 0; mt < 4; ++mt)
                Xf[mt] = *(const bf16x8*)(Xe + (mt * 16 + nlo) * XESTR + (kq << 3));
            #pragma unroll
            for (int mt = 0; mt < 4; ++mt)
                #pragma unroll
                for (int t = 0; t < 2; ++t)
                    accE[mt][t] = __builtin_amdgcn_mfma_f32_16x16x32_bf16(B1e[t], Xf[mt], accE[mt][t], 0, 0, 0);
        }

        // epilogue: Y = relu(accE + b1) -> Us, b64 packed (4 consecutive n)
        #pragma unroll
        for (int mt = 0; mt < 4; ++mt)
            #pragma unroll
            for (int t = 0; t < 2; ++t) {
                uint2 yw;
                yw.x = pkbf(fmaxf(accE[mt][t][0] + b1n[t].x, 0.0f),
                            fmaxf(accE[mt][t][1] + b1n[t].y, 0.0f));
                yw.y = pkbf(fmaxf(accE[mt][t][2] + b1n[t].z, 0.0f),
                            fmaxf(accE[mt][t][3] + b1n[t].w, 0.0f));
                *(uint2*)(Us + (mt * 16 + nlo) * USTR + wave * 32 + t * 16 + (kq << 2)) = yw;
            }
        __syncthreads();                                    // bar2: Y ready

        // ---- Stage 2 (swapped): acc2[n][m] = W2^T x Y^T ----
        f32x4 acc2[4][2];
        #pragma unroll
        for (int mt = 0; mt < 4; ++mt)
            #pragma unroll
            for (int t = 0; t < 2; ++t)
                acc2[mt][t] = (f32x4){0.f, 0.f, 0.f, 0.f};

        #pragma unroll
        for (int kb = 0; kb < 4; ++kb) {
            bf16x8 Yf[4];
            int ko = kb * 32 + (kq << 3);
            #pragma unroll
            for (int mt = 0; mt < 4; ++mt)
                Yf[mt] = *(const bf16x8*)(Us + (mt * 16 + nlo) * USTR + ko);
            #pragma unroll
            for (int mt = 0; mt < 4; ++mt)
                #pragma unroll
                for (int t = 0; t < 2; ++t)
                    acc2[mt][t] = __builtin_amdgcn_mfma_f32_16x16x32_bf16(B2[kb][t], Yf[mt], acc2[mt][t], 0, 0, 0);
        }

        // C = f16(acc2 + b2) -> Cs[m][n], b64 packed (4 consecutive n)
        #pragma unroll
        for (int mt = 0; mt < 4; ++mt)
            #pragma unroll
            for (int t = 0; t < 2; ++t) {
                uint2 cw;
                cw.x = pkf16(acc2[mt][t][0] + b2n[t].x, acc2[mt][t][1] + b2n[t].y);
                cw.y = pkf16(acc2[mt][t][2] + b2n[t].z, acc2[mt][t][3] + b2n[t].w);
                *(uint2*)((unsigned short*)Cs + (size_t)(mt * 16 + nlo) * CSTR + wave * 32 + t * 16 + (kq << 2)) = cw;
            }
        __syncthreads();                                    // bar3: Cs ready -- LAST barrier of the tile

        // A: issue index loads for tile+2G (in flight across the scan)
        int n2 = tile + 2 * EGRID;
        int nb2 = (n2 < NT ? n2 : tile) << 6;
        int i2s0 = srcs[nb2 + er];
        int i2s1 = srcs[nb2 + er + 16];
        int i2s2 = srcs[nb2 + er + 32];
        int i2s3 = srcs[nb2 + er + 48];
        int i2e  = eidx[nb2 + ee];
        int i2d  = dsts[nb2 + lane];

        // C: issue data gathers for tile+G; NO barrier between here and
        // their vmcnt wait at next tile's staging -> latency hides under scan
        bf16x8 q0 = *(const bf16x8*)(U + (size_t)i1s0 * D + (ec << 3));
        bf16x8 q1 = *(const bf16x8*)(U + (size_t)i1s1 * D + (ec << 3));
        bf16x8 q2 = *(const bf16x8*)(U + (size_t)i1s2 * D + (ec << 3));
        bf16x8 q3 = *(const bf16x8*)(U + (size_t)i1s3 * D + (ec << 3));
        float4 qe = *(const float4*)(ea + (size_t)i1e * EF + (eq << 2));
        int nextdd = i1d;

        // segmented run-reduction over sorted dst (R5 ORIGINAL): thread owns
        // one column; 2 groups x 32 rows; one coalesced atomicAdd per flush.
        {
            int col = tid & 127;
            int rbase = (tid >> 7) << 5;            // rows [rbase, rbase+32)
            float sum = 0.f;
            int cur = sDst[buf][rbase];
            for (int i = 0; i < 32; ++i) {
                int d = sDst[buf][rbase + i];       // wave-uniform broadcast
                if (d != cur) {
                    atomicAdd(&agg[(size_t)cur * D + col], sum);
                    sum = 0.f;
                    cur = d;
                }
                sum += (float)Cs[(rbase + i) * CSTR + col];
            }
            atomicAdd(&agg[(size_t)cur * D + col], sum);
        }

        // rotate pipeline registers
        pf0 = q0; pf1 = q1; pf2 = q2; pf3 = q3; pfe = qe; ddcur = nextdd;
        i1s0 = i2s0; i1s1 = i2s1; i1s2 = i2s2; i1s3 = i2s3; i1e = i2e; i1d = i2d;
        buf ^= 1;
    }
}

// out = LayerNorm(h + agg/(1+deg)) * gamma + beta ; one wave per node
__global__ __launch_bounds__(256)
void finalize_kernel(const float* __restrict__ h, const float* __restrict__ agg,
                     const int* __restrict__ cnt,
                     const float* __restrict__ gamma, const float* __restrict__ beta,
                     float* __restrict__ out) {
    int wave = threadIdx.x >> 6, lane = threadIdx.x & 63;
    int v = blockIdx.x * 4 + wave;
    if (v >= V) return;
    float inv = 1.0f / (1.0f + (float)cnt[v]);
    const float* hr = h + (size_t)v * D;
    const float* ar = agg + (size_t)v * D;
    float x0 = hr[lane]      + ar[lane]      * inv;
    float x1 = hr[lane + 64] + ar[lane + 64] * inv;
    float s = x0 + x1;
    #pragma unroll
    for (int m = 32; m; m >>= 1) s += __shfl_xor(s, m);
    float mu = s * (1.0f / 128.0f);
    float d0 = x0 - mu, d1 = x1 - mu;
    float vs = d0 * d0 + d1 * d1;
    #pragma unroll
    for (int m = 32; m; m >>= 1) vs += __shfl_xor(vs, m);
    float rs = rsqrtf(vs * (1.0f / 128.0f) + 1e-5f);
    out[(size_t)v * D + lane]      = d0 * rs * gamma[lane]      + beta[lane];
    out[(size_t)v * D + 64 + lane] = d1 * rs * gamma[lane + 64] + beta[lane + 64];
}

extern "C" void kernel_launch(void* const* d_in, const int* in_sizes, int n_in,
                              void* d_out, int out_size, void* d_ws, size_t ws_size,
                              hipStream_t stream) {
    const float* h     = (const float*)d_in[0];
    const int*   ei    = (const int*)d_in[1];     // [2,E]: row0=src, row1=dst
    const float* ea    = (const float*)d_in[2];
    const float* W1    = (const float*)d_in[3];
    const float* b1    = (const float*)d_in[4];
    const float* W2    = (const float*)d_in[5];
    const float* b2    = (const float*)d_in[6];
    const float* gamma = (const float*)d_in[7];
    const float* beta  = (const float*)d_in[8];
    float* out = (float*)d_out;

    char* ws = (char*)d_ws;
    float*          agg    = (float*)ws;                          // 25,600,000
    int*            cnt    = (int*)(ws + 25600000);               //    200,000 (deg)
    int*            cursor = (int*)(ws + 25800000);               //    200,000
    int*            bsum   = (int*)(ws + 26000000);               //        800
    int*            srcs   = (int*)(ws + 26000800);               //  3,200,000
    int*            dsts   = (int*)(ws + 29200800);               //  3,200,000
    int*            eidx   = (int*)(ws + 32400800);               //  3,200,000
    unsigned short* W1p    = (unsigned short*)(ws + 35600800);    //     40,960
    unsigned short* W2p    = (unsigned short*)(ws + 35641760);    //     32,768
    unsigned short* U      = (unsigned short*)(ws + 35674528);    // 12,800,000

    (void)hipMemsetAsync(cnt, 0, 200000, stream);
    setup_kernel<<<6250, 256, 0, stream>>>(h, ei, cnt, agg, W1, W2, W1p, W2p, U);
    scan1_kernel<<<NSCAN, 256, 0, stream>>>(cnt, cursor, bsum);
    scatter_kernel<<<3125, 256, 0, stream>>>(ei, cursor, bsum, srcs, dsts, eidx);
    edge_kernel<<<EGRID, 256, 0, stream>>>(U, ea, srcs, dsts, eidx, W1p, W2p, b1, b2, agg);
    finalize_kernel<<<12500, 256, 0, stream>>>(h, agg, cnt, gamma, beta, out);
}